// Round 3
// baseline (28.093 us; speedup 1.0000x reference)
//
#include <hip/hip_runtime.h>

#define POLY_N   16777216
#define POLY_DIM 16

// n4 = N/4 float4 elements; 4096 blocks * 256 threads = n4/4 threads,
// each owning 4 float4s at stride Q = n4/4. All 4 loads issued before
// compute -> 4x memory-level parallelism per thread.
#define N4   (POLY_N / 4)          // 4194304
#define NTHR (N4 / 4)              // 1048576
#define GRID (NTHR / 256)          // 4096

// clang native vector type -- accepted by __builtin_nontemporal_*
typedef float f32x4 __attribute__((ext_vector_type(4)));

__global__ __launch_bounds__(256) void poly_horner_kernel(
        const float* __restrict__ x,
        const float* __restrict__ w,
        float* __restrict__ out) {
    float c[POLY_DIM];
#pragma unroll
    for (int i = 0; i < POLY_DIM; ++i) c[i] = w[i];

    const f32x4* __restrict__ x4 = reinterpret_cast<const f32x4*>(x);
    f32x4* __restrict__       o4 = reinterpret_cast<f32x4*>(out);

    const int tid = blockIdx.x * blockDim.x + threadIdx.x;
    const int Q   = NTHR;          // stride between this thread's 4 chunks

    // Issue all 4 loads up front (independent -> 4 in flight).
    f32x4 v0 = __builtin_nontemporal_load(&x4[tid]);
    f32x4 v1 = __builtin_nontemporal_load(&x4[tid + Q]);
    f32x4 v2 = __builtin_nontemporal_load(&x4[tid + 2 * Q]);
    f32x4 v3 = __builtin_nontemporal_load(&x4[tid + 3 * Q]);

    f32x4 r0, r1, r2, r3;
#define HORNER(dst, src)                                              \
    {                                                                 \
        float a = c[POLY_DIM - 1];                                    \
        _Pragma("unroll")                                             \
        for (int j = POLY_DIM - 2; j >= 0; --j) a = fmaf(a, (src), c[j]); \
        (dst) = a;                                                    \
    }
    HORNER(r0.x, v0.x) HORNER(r0.y, v0.y) HORNER(r0.z, v0.z) HORNER(r0.w, v0.w)
    HORNER(r1.x, v1.x) HORNER(r1.y, v1.y) HORNER(r1.z, v1.z) HORNER(r1.w, v1.w)
    HORNER(r2.x, v2.x) HORNER(r2.y, v2.y) HORNER(r2.z, v2.z) HORNER(r2.w, v2.w)
    HORNER(r3.x, v3.x) HORNER(r3.y, v3.y) HORNER(r3.z, v3.z) HORNER(r3.w, v3.w)
#undef HORNER

    __builtin_nontemporal_store(r0, &o4[tid]);
    __builtin_nontemporal_store(r1, &o4[tid + Q]);
    __builtin_nontemporal_store(r2, &o4[tid + 2 * Q]);
    __builtin_nontemporal_store(r3, &o4[tid + 3 * Q]);
}

extern "C" void kernel_launch(void* const* d_in, const int* in_sizes, int n_in,
                              void* d_out, int out_size, void* d_ws, size_t ws_size,
                              hipStream_t stream) {
    const float* x = (const float*)d_in[0];
    const float* w = (const float*)d_in[1];
    float* out     = (float*)d_out;

    poly_horner_kernel<<<GRID, 256, 0, stream>>>(x, w, out);
}

// Round 4
// 24.354 us; speedup vs baseline: 1.1535x; 1.1535x over previous
//
#include <hip/hip_runtime.h>

#define POLY_N   16777216
#define POLY_DIM 16
#define N4       (POLY_N / 4)      // 4194304 float4 elements
#define BLOCK    256
#define GRID     (N4 / BLOCK)      // 16384 blocks, exactly one float4 per thread

typedef float f32x4 __attribute__((ext_vector_type(4)));

__global__ __launch_bounds__(BLOCK) void poly_horner_kernel(
        const float* __restrict__ x,
        const float* __restrict__ w,
        float* __restrict__ out) {
    const f32x4* __restrict__ x4 = reinterpret_cast<const f32x4*>(x);
    f32x4* __restrict__       o4 = reinterpret_cast<f32x4*>(out);

    const int tid = blockIdx.x * BLOCK + threadIdx.x;

    // Issue the data load first; coefficient loads (uniform -> scalar) after,
    // so the vector load is in flight during the s_load chain.
    f32x4 v = x4[tid];

    float c[POLY_DIM];
#pragma unroll
    for (int i = 0; i < POLY_DIM; ++i) c[i] = w[i];

    f32x4 r;
#define HORNER(dst, src)                                                  \
    {                                                                     \
        float a = c[POLY_DIM - 1];                                        \
        _Pragma("unroll")                                                 \
        for (int j = POLY_DIM - 2; j >= 0; --j) a = fmaf(a, (src), c[j]); \
        (dst) = a;                                                        \
    }
    HORNER(r.x, v.x)
    HORNER(r.y, v.y)
    HORNER(r.z, v.z)
    HORNER(r.w, v.w)
#undef HORNER

    o4[tid] = r;
}

extern "C" void kernel_launch(void* const* d_in, const int* in_sizes, int n_in,
                              void* d_out, int out_size, void* d_ws, size_t ws_size,
                              hipStream_t stream) {
    const float* x = (const float*)d_in[0];
    const float* w = (const float*)d_in[1];
    float* out     = (float*)d_out;

    poly_horner_kernel<<<GRID, BLOCK, 0, stream>>>(x, w, out);
}